// Round 14
// baseline (379.642 us; speedup 1.0000x reference)
//
#include <hip/hip_runtime.h>
#include <math.h>

#define T_LEN 65536

#define DROW 72      // bf16 words per staged data row (64 + 8 pad)
#define ASL 392      // shorts per bf16 tile slot (16 rows x 24 + 8 pad)
#define ARS 24       // short row stride inside a bf16 tile (48B, 16B-aligned)
#define BSTR 24      // shorts per B row
#define BSLOT 392    // shorts per B tile
#define BWAVE 2592   // shorts per wave's B region
#define NTS 20       // f32 row stride inside the fact transpose slot
#define K2 8         // stage-2 chunk length
#define W2 24        // stage-2 warm-up steps
#define PD 8         // stage-2 prefetch ring depth

typedef __attribute__((ext_vector_type(8))) short bh8;
typedef __attribute__((ext_vector_type(4))) float f4;

__device__ __forceinline__ unsigned short f2bf(float x) {
    union { float f; unsigned u; } v; v.f = x;
    return (unsigned short)((v.u + 0x7FFFu + ((v.u >> 16) & 1u)) >> 16);  // RNE
}
__device__ __forceinline__ float bf2f(unsigned short s) {
    union { unsigned u; float f; } v; v.u = ((unsigned)s) << 16; return v.f;
}

// broadcast lane J's value to all lanes within each 16-lane group (BitMode swizzle)
template<int J>
__device__ __forceinline__ float bc16(float v) {
    return __int_as_float(__builtin_amdgcn_ds_swizzle(__float_as_int(v), (J << 5) | 0x10));
}
__device__ __forceinline__ float bc16i(float v, int J) {
    switch (J) {
        case 0:  return bc16<0>(v);  case 1:  return bc16<1>(v);
        case 2:  return bc16<2>(v);  case 3:  return bc16<3>(v);
        case 4:  return bc16<4>(v);  case 5:  return bc16<5>(v);
        case 6:  return bc16<6>(v);  case 7:  return bc16<7>(v);
        case 8:  return bc16<8>(v);  case 9:  return bc16<9>(v);
        case 10: return bc16<10>(v); case 11: return bc16<11>(v);
        case 12: return bc16<12>(v); case 13: return bc16<13>(v);
        case 14: return bc16<14>(v); default: return bc16<15>(v);
    }
}

// ---- one-time weight swizzle + entropy-accumulator zeroing ----
__global__ void wswz_kernel(const float* __restrict__ Wmu, const float* __restrict__ WL,
                            const float* __restrict__ WLx, short* __restrict__ Wsw,
                            float* __restrict__ entOut)
{
    if (blockIdx.x == 0 && threadIdx.x == 0) *entOut = 0.0f;
    int idx = blockIdx.x * 256 + threadIdx.x;   // 0 .. 66*512-1
    int f = idx >> 9, r = idx & 511;
    int lane = r >> 3, j = r & 7;
    int ks = f & 1, job = f >> 1;
    int k = ks * 32 + ((lane >> 4) << 3) + j;
    int n = job * 16 + (lane & 15);
    float v = (n < 16) ? Wmu[k * 16 + n]
            : (n < 272) ? WL[k * 256 + (n - 16)]
            : WLx[k * 256 + (n - 272)];
    Wsw[idx] = (short)f2bf(v);
}

// ================= Kernel A: pure-MFMA recognition + tile algebra ==========
__global__ __launch_bounds__(256) __attribute__((amdgpu_waves_per_eu(4, 4)))
void vilds_gemm(const float* __restrict__ data, const short* __restrict__ Wsw,
                const float* __restrict__ bmu, const float* __restrict__ bL,
                const float* __restrict__ bLx,
                float* __restrict__ Sbuf, unsigned short* __restrict__ Cbuf,
                float* __restrict__ PXbuf)
{
    __shared__ short Dt[17 * DROW];                 // staged data rows
    __shared__ __align__(16) short AglS[16 * ASL];  // A tiles bf16 -> C bounce
    __shared__ __align__(16) short Bsh[4 * BWAVE];  // B tiles bf16

    const int tid = threadIdx.x;
    const int t0 = blockIdx.x * 16;

    for (int idx = tid; idx < 17 * 16; idx += 256) {
        int row = idx >> 4, c4 = idx & 15;
        int tr = t0 + row;
        float4 dv = (tr < T_LEN) ? ((const float4*)data)[(size_t)tr * 16 + c4]
                                 : make_float4(0.f, 0.f, 0.f, 0.f);
        short4 b;
        b.x = (short)f2bf(dv.x); b.y = (short)f2bf(dv.y);
        b.z = (short)f2bf(dv.z); b.w = (short)f2bf(dv.w);
        *(short4*)&Dt[row * DROW + c4 * 4] = b;
    }
    __syncthreads();

    const int wv = tid >> 6, lane = tid & 63;
    const int col = lane & 15, quad = lane >> 4;

    // ---- recognition GEMM: jobs 0=postX, 1..16=A rows, 17..32=B rows ----
    {
        bh8 a00 = *(const bh8*)&Dt[col * DROW + quad * 8];
        bh8 a01 = *(const bh8*)&Dt[col * DROW + quad * 8 + 32];
        bh8 a10 = *(const bh8*)&Dt[(col + 1) * DROW + quad * 8];
        bh8 a11 = *(const bh8*)&Dt[(col + 1) * DROW + quad * 8 + 32];
        for (int job = wv; job < 33; job += 4) {
            const int isB = (job >= 17);
            bh8 b0 = *(const bh8*)&Wsw[(job * 2 + 0) * 512 + lane * 8];
            bh8 b1 = *(const bh8*)&Wsw[(job * 2 + 1) * 512 + lane * 8];
            float bias;
            if (job == 0)      bias = bmu[col];
            else if (!isB)     bias = bL[(job - 1) * 16 + col] + ((col == job - 1) ? 3.0f : 0.0f);
            else               bias = bLx[(job - 17) * 16 + col];
            f4 acc = { bias, bias, bias, bias };
            acc = __builtin_amdgcn_mfma_f32_16x16x32_bf16(isB ? a10 : a00, b0, acc, 0, 0, 0);
            acc = __builtin_amdgcn_mfma_f32_16x16x32_bf16(isB ? a11 : a01, b1, acc, 0, 0, 0);
            if (job == 0) {
                #pragma unroll
                for (int r = 0; r < 4; ++r)
                    PXbuf[(size_t)(t0 + quad * 4 + r) * 16 + col] = acc[r];
            } else if (!isB) {
                int i = job - 1;
                #pragma unroll
                for (int r = 0; r < 4; ++r)
                    AglS[(quad * 4 + r) * ASL + i * ARS + col] = (short)f2bf(acc[r]);
            } else {
                int i = job - 17;
                #pragma unroll
                for (int r = 0; r < 4; ++r) {
                    int tw = quad * 4 + r;
                    Bsh[(tw >> 2) * BWAVE + (tw & 3) * BSLOT + i * BSTR + col] = (short)f2bf(acc[r]);
                }
            }
        }
    }
    __syncthreads();

    const bh8 zero8 = (bh8){0, 0, 0, 0, 0, 0, 0, 0};

    // ---- per-wave MFMA: S = A A^T + eps I -> Sbuf; C1n = -(B A^T) -> Cbuf ----
    #pragma unroll
    for (int tt = 0; tt < 4; ++tt) {
        int sl = wv * 4 + tt;
        size_t t = (size_t)(t0 + sl);
        bh8 af = *(const bh8*)&AglS[sl * ASL + col * ARS + (quad & 1) * 8];
        bh8 bf = *(const bh8*)&Bsh[wv * BWAVE + tt * BSLOT + col * BSTR + (quad & 1) * 8];
        bh8 az = (quad < 2) ? af : zero8;
        bh8 bz = (quad < 2) ? bf : zero8;
        f4 accS = { (quad * 4 + 0 == col) ? 1e-6f : 0.f, (quad * 4 + 1 == col) ? 1e-6f : 0.f,
                    (quad * 4 + 2 == col) ? 1e-6f : 0.f, (quad * 4 + 3 == col) ? 1e-6f : 0.f };
        accS = __builtin_amdgcn_mfma_f32_16x16x32_bf16(az, af, accS, 0, 0, 0);
        f4 accC = { 0.f, 0.f, 0.f, 0.f };
        accC = __builtin_amdgcn_mfma_f32_16x16x32_bf16(bz, af, accC, 0, 0, 0);
        // S col-major per t: Sbuf[t*256 + col*16 + row]
        *(f4*)&Sbuf[t * 256 + col * 16 + quad * 4] = accS;
        // C1n: bounce bf16 through AglS slot sl (dead after af read), coalesced store
        #pragma unroll
        for (int r = 0; r < 4; ++r)
            AglS[sl * ASL + (quad * 4 + r) * ARS + col] = (short)f2bf(-accC[r]);
        short4 cv = *(const short4*)&AglS[sl * ASL + col * ARS + quad * 4];
        *(short4*)&Cbuf[t * 256 + col * 16 + quad * 4] = cv;
    }
}

// ================= Kernel B: serial chol + solves, ZERO MFMA ===============
// R13 lesson: LDS-read bsolve (change 2) pushed live regs past the 128 cap
// -> 500MB spill, 3x slower. R14 keeps ONLY change 1: forward solve FUSED
// into chol (deletes 136 swizzles; chol-phase live = s+zc ~32, well under
// the peak). Backward solve reverted to R11's swizzle form (peak phase
// measured 108 VGPR, zero spill). Allocation law: cap = 256/waves_min ->
// waves_min=2.
__global__ __launch_bounds__(256) __attribute__((amdgpu_waves_per_eu(2, 4)))
void vilds_fact(const float* __restrict__ Sbuf, const unsigned short* __restrict__ Cbuf,
                const float* __restrict__ ns, unsigned short* __restrict__ Nbuf,
                float* __restrict__ Ubuf, float* __restrict__ entOut)
{
    __shared__ float Ntr[16 * 16 * NTS];        // 16 group transpose slots (20KB)
    __shared__ float NsL[256];
    __shared__ float esh[4];

    const int tid = threadIdx.x;
    const int t0 = blockIdx.x * 16;
    const int gg = tid >> 4, li = tid & 15, wv = tid >> 6;
    const int t = t0 + gg;

    NsL[tid] = ns[(size_t)t0 * 16 + tid];       // coalesced; consumed group-locally

    // hoist the C row load (forward-solve RHS) so HBM latency hides under chol
    bh8 cb0 = *(const bh8*)&Cbuf[(size_t)t * 256 + li * 16];
    bh8 cb1 = *(const bh8*)&Cbuf[(size_t)t * 256 + li * 16 + 8];

    // load S row li (== col li, symmetric): 64B contiguous per lane
    float s[16];
    {
        const f4* Sp = (const f4*)&Sbuf[(size_t)t * 256 + li * 16];
        #pragma unroll
        for (int c = 0; c < 4; ++c) {
            f4 v = Sp[c];
            s[4 * c + 0] = v[0]; s[4 * c + 1] = v[1]; s[4 * c + 2] = v[2]; s[4 * c + 3] = v[3];
        }
    }

    // RHS c = C1n row li (decoded; becomes z during the fused loop)
    float zc[16];
    #pragma unroll
    for (int k = 0; k < 8; ++k) {
        zc[k]     = bf2f((unsigned short)cb0[k]);
        zc[k + 8] = bf2f((unsigned short)cb1[k]);
    }

    // Cholesky FUSED with forward solve (R13 change 1, correctness-verified):
    //   step k: z_k = c[k]*inv;  for j>k:  b = bc(s[k], j)
    //           s[j]  -= (s[k]*inv^2) * b     (Schur trailing update)
    //           zc[j] -= (z_k*inv) * b        (forward substitution)
    float ent = 0.0f;
    #pragma unroll
    for (int k = 0; k < 16; ++k) {
        float dkk = fmaxf(bc16i(s[k], k), 1e-20f);
        float inv = rsqrtf(dkk);
        if (li == k) ent = 0.5f * __logf(dkk);
        float a  = s[k] * (inv * inv);
        float zk = zc[k] * inv;
        zc[k] = zk;
        float w2 = zk * inv;
        #pragma unroll
        for (int j = k + 1; j < 16; ++j) {
            float b = bc16i(s[k], j);           // lane j's residual col k
            s[j]  = fmaf(-a,  b, s[j]);
            zc[j] = fmaf(-w2, b, zc[j]);
        }
        s[k] *= inv;                            // finalize G[li][k]
    }
    // lane li holds row li of G in s[]; zc[] = z = G^{-1} c

    // backward solve (N column li in zc) merged with u-solve — R11's swizzle
    // form (proven 108-VGPR, no-spill phase)
    {
        float uu[16];
        #pragma unroll
        for (int c = 0; c < 16; ++c) uu[c] = NsL[gg * 16 + c];
        #pragma unroll
        for (int ii = 0; ii < 16; ++ii) {
            const int i = 15 - ii;
            float sx0 = 0.f, sx1 = 0.f, su0 = 0.f, su1 = 0.f;
            #pragma unroll
            for (int m = i + 1; m < 16; ++m) {
                float g = bc16i(s[i], m);       // G[m][i]
                if ((m - i) & 1) { sx0 = fmaf(g, zc[m], sx0); su0 = fmaf(g, uu[m], su0); }
                else             { sx1 = fmaf(g, zc[m], sx1); su1 = fmaf(g, uu[m], su1); }
            }
            float gii = bc16i(s[i], i);
            float inv = rsqrtf(gii * gii);      // 1/G[i][i], G[i][i] > 0
            zc[i] = (zc[i] - (sx0 + sx1)) * inv;    // N[i][li]
            uu[i] = (uu[i] - (su0 + su1)) * inv;
        }
        if (li == 0) {
            f4* U4 = (f4*)&Ubuf[(size_t)t * 16];
            f4 u0 = { uu[0], uu[1], uu[2], uu[3] };
            f4 u1 = { uu[4], uu[5], uu[6], uu[7] };
            f4 u2 = { uu[8], uu[9], uu[10], uu[11] };
            f4 u3 = { uu[12], uu[13], uu[14], uu[15] };
            U4[0] = u0; U4[1] = u1; U4[2] = u2; U4[3] = u3;
        }
    }

    // transpose N through this group's LDS slot, then coalesced 32B bf16 store
    {
        float* Gt = Ntr + (size_t)gg * 16 * NTS;    // group slot: 16 rows x NTS
        #pragma unroll
        for (int c = 0; c < 4; ++c) {
            f4 v = { zc[4 * c + 0], zc[4 * c + 1], zc[4 * c + 2], zc[4 * c + 3] };
            *(f4*)&Gt[li * NTS + c * 4] = v;        // Gt[li][k] = N[k][li]
        }
        if (t < T_LEN - 1) {
            unsigned pk[8];
            #pragma unroll
            for (int jj = 0; jj < 8; ++jj) {
                unsigned short lo = f2bf(Gt[(2 * jj)     * NTS + li]);  // N[li][2jj]
                unsigned short hi = f2bf(Gt[(2 * jj + 1) * NTS + li]);
                pk[jj] = (unsigned)lo | ((unsigned)hi << 16);
            }
            uint4 v0 = { pk[0], pk[1], pk[2], pk[3] };
            uint4 v1 = { pk[4], pk[5], pk[6], pk[7] };
            unsigned short* np = &Nbuf[(size_t)t * 256 + li * 16];
            *(uint4*)np = v0;
            *(uint4*)(np + 8) = v1;
        }
    }

    // entropy: wave reduce -> LDS partials -> ONE atomic per block
    float esum = ent;
    #pragma unroll
    for (int off = 1; off < 64; off <<= 1)
        esum += __shfl_xor(esum, off, 64);
    if ((tid & 63) == 0) esh[wv] = esum;
    __syncthreads();
    if (tid == 0) atomicAdd(entOut, -(esh[0] + esh[1] + esh[2] + esh[3]));
}

// ---- backward recurrence x_t = u_t + N_t x_{t+1} (unchanged) ----
__global__ __launch_bounds__(64) __attribute__((amdgpu_waves_per_eu(2, 2)))
void vilds_stage2(const unsigned short* __restrict__ Nbuf, const float* __restrict__ Ubuf,
                  const float* __restrict__ PXbuf, float* __restrict__ out)
{
    const int lane = threadIdx.x;        // 0..63
    const int li = lane & 15;            // output row
    const int g  = lane >> 4;            // chunk within block
    const int ch = blockIdx.x * 4 + g;
    const int a  = ch * K2;
    int ts = a + K2 - 1 + W2;
    if (ts > T_LEN - 1) ts = T_LEN - 1;

    float x = Ubuf[(size_t)ts * 16 + li];           // exact at t=T-1
    if (ts < a + K2)
        out[1 + (size_t)ts * 16 + li] = x + PXbuf[(size_t)ts * 16 + li];

    uint4 nA[PD], nB[PD]; float ub[PD], pxb[PD];
    #pragma unroll
    for (int p = 0; p < PD; ++p) {
        int tt = ts - 1 - p;
        if (tt >= a) {
            const unsigned short* rp = &Nbuf[(size_t)tt * 256 + li * 16];
            nA[p]  = *(const uint4*)rp;
            nB[p]  = *(const uint4*)(rp + 8);
            ub[p]  = Ubuf[(size_t)tt * 16 + li];
            pxb[p] = PXbuf[(size_t)tt * 16 + li];
        }
    }

    const int DMAX = K2 - 1 + W2;                   // steps after the head
    for (int db = 1; db <= DMAX; db += PD) {
        #pragma unroll
        for (int q = 0; q < PD; ++q) {
            int t = ts - (db + q);
            if (t >= a) {
                uint4 ra = nA[q], rb = nB[q];
                float ut = ub[q], pxt = pxb[q];
                int tp = t - PD;
                if (tp >= a) {                      // refill ring slot
                    const unsigned short* rp = &Nbuf[(size_t)tp * 256 + li * 16];
                    nA[q]  = *(const uint4*)rp;
                    nB[q]  = *(const uint4*)(rp + 8);
                    ub[q]  = Ubuf[(size_t)tp * 16 + li];
                    pxb[q] = PXbuf[(size_t)tp * 16 + li];
                }
                #define NVL(w) bf2f((unsigned short)((w) & 0xffffu))
                #define NVH(w) bf2f((unsigned short)((w) >> 16))
                float s0 = NVL(ra.x) * bc16<0>(x);
                float s1 = NVH(ra.x) * bc16<1>(x);
                float s2 = NVL(ra.y) * bc16<2>(x);
                float s3 = NVH(ra.y) * bc16<3>(x);
                s0 = fmaf(NVL(ra.z), bc16<4>(x),  s0);
                s1 = fmaf(NVH(ra.z), bc16<5>(x),  s1);
                s2 = fmaf(NVL(ra.w), bc16<6>(x),  s2);
                s3 = fmaf(NVH(ra.w), bc16<7>(x),  s3);
                s0 = fmaf(NVL(rb.x), bc16<8>(x),  s0);
                s1 = fmaf(NVH(rb.x), bc16<9>(x),  s1);
                s2 = fmaf(NVL(rb.y), bc16<10>(x), s2);
                s3 = fmaf(NVH(rb.y), bc16<11>(x), s3);
                s0 = fmaf(NVL(rb.z), bc16<12>(x), s0);
                s1 = fmaf(NVH(rb.z), bc16<13>(x), s1);
                s2 = fmaf(NVL(rb.w), bc16<14>(x), s2);
                s3 = fmaf(NVH(rb.w), bc16<15>(x), s3);
                #undef NVL
                #undef NVH
                x = ut + ((s0 + s1) + (s2 + s3));   // x_t[li]
                if (t < a + K2)
                    out[1 + (size_t)t * 16 + li] = x + pxt;
            }
        }
    }
}

extern "C" void kernel_launch(void* const* d_in, const int* in_sizes, int n_in,
                              void* d_out, int out_size, void* d_ws, size_t ws_size,
                              hipStream_t stream)
{
    const float* data = (const float*)d_in[0];
    const float* Wmu  = (const float*)d_in[1];
    const float* bmu  = (const float*)d_in[2];
    const float* WL   = (const float*)d_in[3];
    const float* bL   = (const float*)d_in[4];
    const float* WLx  = (const float*)d_in[5];
    const float* bLx  = (const float*)d_in[6];
    const float* ns   = (const float*)d_in[7];
    float* out = (float*)d_out;

    unsigned short* Nbuf = (unsigned short*)d_ws;                 // T*256 bf16  (33.5 MB)
    float* Ubuf  = (float*)(Nbuf + (size_t)T_LEN * 256);          // T*16 f32    (4.2 MB)
    float* PXbuf = Ubuf + (size_t)T_LEN * 16;                     // T*16 f32    (4.2 MB)
    float* Sbuf  = PXbuf + (size_t)T_LEN * 16;                    // T*256 f32   (67 MB)
    unsigned short* Cbuf = (unsigned short*)(Sbuf + (size_t)T_LEN * 256); // T*256 bf16 (33.5 MB)
    short* Wsw   = (short*)(Cbuf + (size_t)T_LEN * 256);          // 66*512 bf16

    wswz_kernel<<<dim3(132), dim3(256), 0, stream>>>(Wmu, WL, WLx, Wsw, out);
    vilds_gemm<<<dim3(T_LEN / 16), dim3(256), 0, stream>>>(
        data, Wsw, bmu, bL, bLx, Sbuf, Cbuf, PXbuf);
    vilds_fact<<<dim3(T_LEN / 16), dim3(256), 0, stream>>>(
        Sbuf, Cbuf, ns, Nbuf, Ubuf, out);
    vilds_stage2<<<dim3(T_LEN / (K2 * 4)), dim3(64), 0, stream>>>(Nbuf, Ubuf, PXbuf, out);
}

// Round 15
// 191.141 us; speedup vs baseline: 1.9862x; 1.9862x over previous
//
#include <hip/hip_runtime.h>
#include <math.h>

#define T_LEN 65536

#define DROW 72      // bf16 words per staged data row (64 + 8 pad)
#define ASL 392      // shorts per bf16 tile slot (16 rows x 24 + 8 pad)
#define ARS 24       // short row stride inside a bf16 tile (48B, 16B-aligned)
#define BSTR 24      // shorts per B row
#define BSLOT 392    // shorts per B tile
#define BWAVE 2592   // shorts per wave's B region
#define NTS 20       // f32 row stride inside the fact transpose slot
#define K2 8         // stage-2 chunk length
#define W2 16        // stage-2 warm-up steps (R15: 24->16, -26% steps; ||N||^16 ~ 1e-5)
#define PD 8         // stage-2 prefetch ring depth

typedef __attribute__((ext_vector_type(8))) short bh8;
typedef __attribute__((ext_vector_type(4))) float f4;

__device__ __forceinline__ unsigned short f2bf(float x) {
    union { float f; unsigned u; } v; v.f = x;
    return (unsigned short)((v.u + 0x7FFFu + ((v.u >> 16) & 1u)) >> 16);  // RNE
}
__device__ __forceinline__ float bf2f(unsigned short s) {
    union { unsigned u; float f; } v; v.u = ((unsigned)s) << 16; return v.f;
}

// broadcast lane J's value to all lanes within each 16-lane group (BitMode swizzle)
template<int J>
__device__ __forceinline__ float bc16(float v) {
    return __int_as_float(__builtin_amdgcn_ds_swizzle(__float_as_int(v), (J << 5) | 0x10));
}
__device__ __forceinline__ float bc16i(float v, int J) {
    switch (J) {
        case 0:  return bc16<0>(v);  case 1:  return bc16<1>(v);
        case 2:  return bc16<2>(v);  case 3:  return bc16<3>(v);
        case 4:  return bc16<4>(v);  case 5:  return bc16<5>(v);
        case 6:  return bc16<6>(v);  case 7:  return bc16<7>(v);
        case 8:  return bc16<8>(v);  case 9:  return bc16<9>(v);
        case 10: return bc16<10>(v); case 11: return bc16<11>(v);
        case 12: return bc16<12>(v); case 13: return bc16<13>(v);
        case 14: return bc16<14>(v); default: return bc16<15>(v);
    }
}

// ---- one-time weight swizzle + entropy-accumulator zeroing ----
__global__ void wswz_kernel(const float* __restrict__ Wmu, const float* __restrict__ WL,
                            const float* __restrict__ WLx, short* __restrict__ Wsw,
                            float* __restrict__ entOut)
{
    if (blockIdx.x == 0 && threadIdx.x == 0) *entOut = 0.0f;
    int idx = blockIdx.x * 256 + threadIdx.x;   // 0 .. 66*512-1
    int f = idx >> 9, r = idx & 511;
    int lane = r >> 3, j = r & 7;
    int ks = f & 1, job = f >> 1;
    int k = ks * 32 + ((lane >> 4) << 3) + j;
    int n = job * 16 + (lane & 15);
    float v = (n < 16) ? Wmu[k * 16 + n]
            : (n < 272) ? WL[k * 256 + (n - 16)]
            : WLx[k * 256 + (n - 272)];
    Wsw[idx] = (short)f2bf(v);
}

// ================= Kernel A: pure-MFMA recognition + tile algebra ==========
__global__ __launch_bounds__(256) __attribute__((amdgpu_waves_per_eu(4, 4)))
void vilds_gemm(const float* __restrict__ data, const short* __restrict__ Wsw,
                const float* __restrict__ bmu, const float* __restrict__ bL,
                const float* __restrict__ bLx,
                float* __restrict__ Sbuf, unsigned short* __restrict__ Cbuf,
                float* __restrict__ PXbuf)
{
    __shared__ short Dt[17 * DROW];                 // staged data rows
    __shared__ __align__(16) short AglS[16 * ASL];  // A tiles bf16 -> C bounce
    __shared__ __align__(16) short Bsh[4 * BWAVE];  // B tiles bf16

    const int tid = threadIdx.x;
    const int t0 = blockIdx.x * 16;

    for (int idx = tid; idx < 17 * 16; idx += 256) {
        int row = idx >> 4, c4 = idx & 15;
        int tr = t0 + row;
        float4 dv = (tr < T_LEN) ? ((const float4*)data)[(size_t)tr * 16 + c4]
                                 : make_float4(0.f, 0.f, 0.f, 0.f);
        short4 b;
        b.x = (short)f2bf(dv.x); b.y = (short)f2bf(dv.y);
        b.z = (short)f2bf(dv.z); b.w = (short)f2bf(dv.w);
        *(short4*)&Dt[row * DROW + c4 * 4] = b;
    }
    __syncthreads();

    const int wv = tid >> 6, lane = tid & 63;
    const int col = lane & 15, quad = lane >> 4;

    // ---- recognition GEMM: jobs 0=postX, 1..16=A rows, 17..32=B rows ----
    {
        bh8 a00 = *(const bh8*)&Dt[col * DROW + quad * 8];
        bh8 a01 = *(const bh8*)&Dt[col * DROW + quad * 8 + 32];
        bh8 a10 = *(const bh8*)&Dt[(col + 1) * DROW + quad * 8];
        bh8 a11 = *(const bh8*)&Dt[(col + 1) * DROW + quad * 8 + 32];
        for (int job = wv; job < 33; job += 4) {
            const int isB = (job >= 17);
            bh8 b0 = *(const bh8*)&Wsw[(job * 2 + 0) * 512 + lane * 8];
            bh8 b1 = *(const bh8*)&Wsw[(job * 2 + 1) * 512 + lane * 8];
            float bias;
            if (job == 0)      bias = bmu[col];
            else if (!isB)     bias = bL[(job - 1) * 16 + col] + ((col == job - 1) ? 3.0f : 0.0f);
            else               bias = bLx[(job - 17) * 16 + col];
            f4 acc = { bias, bias, bias, bias };
            acc = __builtin_amdgcn_mfma_f32_16x16x32_bf16(isB ? a10 : a00, b0, acc, 0, 0, 0);
            acc = __builtin_amdgcn_mfma_f32_16x16x32_bf16(isB ? a11 : a01, b1, acc, 0, 0, 0);
            if (job == 0) {
                #pragma unroll
                for (int r = 0; r < 4; ++r)
                    PXbuf[(size_t)(t0 + quad * 4 + r) * 16 + col] = acc[r];
            } else if (!isB) {
                int i = job - 1;
                #pragma unroll
                for (int r = 0; r < 4; ++r)
                    AglS[(quad * 4 + r) * ASL + i * ARS + col] = (short)f2bf(acc[r]);
            } else {
                int i = job - 17;
                #pragma unroll
                for (int r = 0; r < 4; ++r) {
                    int tw = quad * 4 + r;
                    Bsh[(tw >> 2) * BWAVE + (tw & 3) * BSLOT + i * BSTR + col] = (short)f2bf(acc[r]);
                }
            }
        }
    }
    __syncthreads();

    const bh8 zero8 = (bh8){0, 0, 0, 0, 0, 0, 0, 0};

    // ---- per-wave MFMA: S = A A^T + eps I -> Sbuf; C1n = -(B A^T) -> Cbuf ----
    #pragma unroll
    for (int tt = 0; tt < 4; ++tt) {
        int sl = wv * 4 + tt;
        size_t t = (size_t)(t0 + sl);
        bh8 af = *(const bh8*)&AglS[sl * ASL + col * ARS + (quad & 1) * 8];
        bh8 bf = *(const bh8*)&Bsh[wv * BWAVE + tt * BSLOT + col * BSTR + (quad & 1) * 8];
        bh8 az = (quad < 2) ? af : zero8;
        bh8 bz = (quad < 2) ? bf : zero8;
        f4 accS = { (quad * 4 + 0 == col) ? 1e-6f : 0.f, (quad * 4 + 1 == col) ? 1e-6f : 0.f,
                    (quad * 4 + 2 == col) ? 1e-6f : 0.f, (quad * 4 + 3 == col) ? 1e-6f : 0.f };
        accS = __builtin_amdgcn_mfma_f32_16x16x32_bf16(az, af, accS, 0, 0, 0);
        f4 accC = { 0.f, 0.f, 0.f, 0.f };
        accC = __builtin_amdgcn_mfma_f32_16x16x32_bf16(bz, af, accC, 0, 0, 0);
        // S col-major per t: Sbuf[t*256 + col*16 + row]
        *(f4*)&Sbuf[t * 256 + col * 16 + quad * 4] = accS;
        // C1n: bounce bf16 through AglS slot sl (dead after af read), coalesced store
        #pragma unroll
        for (int r = 0; r < 4; ++r)
            AglS[sl * ASL + (quad * 4 + r) * ARS + col] = (short)f2bf(-accC[r]);
        short4 cv = *(const short4*)&AglS[sl * ASL + col * ARS + quad * 4];
        *(short4*)&Cbuf[t * 256 + col * 16 + quad * 4] = cv;
    }
}

// ================= Kernel B: serial chol + solves, ZERO MFMA ===============
// EXACT R11/R12 version (measured twice: 67us, 108 VGPR, zero spill).
// R13/R14 lesson: this kernel has ZERO register headroom at the 128-reg cap
// (waves_min=2); any restructuring that extends a 16-float array's live
// range across a phase boundary spills and costs 3x. Do not touch.
__global__ __launch_bounds__(256) __attribute__((amdgpu_waves_per_eu(2, 4)))
void vilds_fact(const float* __restrict__ Sbuf, const unsigned short* __restrict__ Cbuf,
                const float* __restrict__ ns, unsigned short* __restrict__ Nbuf,
                float* __restrict__ Ubuf, float* __restrict__ entOut)
{
    __shared__ float Ntr[16 * 16 * NTS];        // 16 group transpose slots (20KB)
    __shared__ float NsL[256];
    __shared__ float esh[4];

    const int tid = threadIdx.x;
    const int t0 = blockIdx.x * 16;
    const int gg = tid >> 4, li = tid & 15, wv = tid >> 6;
    const int t = t0 + gg;

    NsL[tid] = ns[(size_t)t0 * 16 + tid];       // coalesced; consumed group-locally

    // hoist the C row load (forward-solve RHS) so HBM latency hides under chol
    bh8 cb0 = *(const bh8*)&Cbuf[(size_t)t * 256 + li * 16];
    bh8 cb1 = *(const bh8*)&Cbuf[(size_t)t * 256 + li * 16 + 8];

    // load S row li (== col li, symmetric): 64B contiguous per lane
    float s[16];
    {
        const f4* Sp = (const f4*)&Sbuf[(size_t)t * 256 + li * 16];
        #pragma unroll
        for (int c = 0; c < 4; ++c) {
            f4 v = Sp[c];
            s[4 * c + 0] = v[0]; s[4 * c + 1] = v[1]; s[4 * c + 2] = v[2]; s[4 * c + 3] = v[3];
        }
    }

    // Cholesky, short-chain form (broadcast unscaled residual, fold 1/d)
    float ent = 0.0f;
    #pragma unroll
    for (int k = 0; k < 16; ++k) {
        float dkk = fmaxf(bc16i(s[k], k), 1e-20f);
        float inv = rsqrtf(dkk);
        if (li == k) ent = 0.5f * __logf(dkk);
        float a = s[k] * (inv * inv);
        #pragma unroll
        for (int j = k + 1; j < 16; ++j)
            s[j] = fmaf(-a, bc16i(s[k], j), s[j]);
        s[k] *= inv;
    }
    // lane li holds row li of G in s[]

    // forward solve: G z = c  (c = C1n row li)
    float zx[16];
    #pragma unroll
    for (int i = 0; i < 16; ++i) {
        float acc0 = bf2f((unsigned short)(i < 8 ? cb0[i] : cb1[i - 8]));
        float acc1 = 0.f;
        #pragma unroll
        for (int m = 0; m < i; ++m) {
            float gim = bc16i(s[m], i);             // G[i][m]
            if ((i - m) & 1) acc0 = fmaf(-gim, zx[m], acc0);
            else             acc1 = fmaf(-gim, zx[m], acc1);
        }
        float gii = bc16i(s[i], i);
        float inv = rsqrtf(gii * gii);              // 1/G[i][i]
        zx[i] = (acc0 + acc1) * inv;
    }

    // backward solve (N column li) merged with u-solve (same broadcasts)
    {
        float uu[16];
        #pragma unroll
        for (int c = 0; c < 16; ++c) uu[c] = NsL[gg * 16 + c];
        #pragma unroll
        for (int ii = 0; ii < 16; ++ii) {
            const int i = 15 - ii;
            float sx0 = 0.f, sx1 = 0.f, su0 = 0.f, su1 = 0.f;
            #pragma unroll
            for (int m = i + 1; m < 16; ++m) {
                float g = bc16i(s[i], m);           // G[m][i]
                if ((m - i) & 1) { sx0 = fmaf(g, zx[m], sx0); su0 = fmaf(g, uu[m], su0); }
                else             { sx1 = fmaf(g, zx[m], sx1); su1 = fmaf(g, uu[m], su1); }
            }
            float gii = bc16i(s[i], i);
            float inv = rsqrtf(gii * gii);
            zx[i] = (zx[i] - (sx0 + sx1)) * inv;    // N[i][li]
            uu[i] = (uu[i] - (su0 + su1)) * inv;
        }
        if (li == 0) {
            f4* U4 = (f4*)&Ubuf[(size_t)t * 16];
            f4 u0 = { uu[0], uu[1], uu[2], uu[3] };
            f4 u1 = { uu[4], uu[5], uu[6], uu[7] };
            f4 u2 = { uu[8], uu[9], uu[10], uu[11] };
            f4 u3 = { uu[12], uu[13], uu[14], uu[15] };
            U4[0] = u0; U4[1] = u1; U4[2] = u2; U4[3] = u3;
        }
    }

    // transpose N through this group's LDS slot, then coalesced 32B bf16 store
    {
        float* Gt = Ntr + (size_t)gg * 16 * NTS;    // group slot: 16 rows x NTS
        #pragma unroll
        for (int c = 0; c < 4; ++c) {
            f4 v = { zx[4 * c + 0], zx[4 * c + 1], zx[4 * c + 2], zx[4 * c + 3] };
            *(f4*)&Gt[li * NTS + c * 4] = v;        // Gt[li][k] = N[k][li]
        }
        if (t < T_LEN - 1) {
            unsigned pk[8];
            #pragma unroll
            for (int jj = 0; jj < 8; ++jj) {
                unsigned short lo = f2bf(Gt[(2 * jj)     * NTS + li]);  // N[li][2jj]
                unsigned short hi = f2bf(Gt[(2 * jj + 1) * NTS + li]);
                pk[jj] = (unsigned)lo | ((unsigned)hi << 16);
            }
            uint4 v0 = { pk[0], pk[1], pk[2], pk[3] };
            uint4 v1 = { pk[4], pk[5], pk[6], pk[7] };
            unsigned short* np = &Nbuf[(size_t)t * 256 + li * 16];
            *(uint4*)np = v0;
            *(uint4*)(np + 8) = v1;
        }
    }

    // entropy: wave reduce -> LDS partials -> ONE atomic per block
    float esum = ent;
    #pragma unroll
    for (int off = 1; off < 64; off <<= 1)
        esum += __shfl_xor(esum, off, 64);
    if ((tid & 63) == 0) esh[wv] = esum;
    __syncthreads();
    if (tid == 0) atomicAdd(entOut, -(esh[0] + esh[1] + esh[2] + esh[3]));
}

// ---- backward recurrence x_t = u_t + N_t x_{t+1} ----
__global__ __launch_bounds__(64) __attribute__((amdgpu_waves_per_eu(2, 2)))
void vilds_stage2(const unsigned short* __restrict__ Nbuf, const float* __restrict__ Ubuf,
                  const float* __restrict__ PXbuf, float* __restrict__ out)
{
    const int lane = threadIdx.x;        // 0..63
    const int li = lane & 15;            // output row
    const int g  = lane >> 4;            // chunk within block
    const int ch = blockIdx.x * 4 + g;
    const int a  = ch * K2;
    int ts = a + K2 - 1 + W2;
    if (ts > T_LEN - 1) ts = T_LEN - 1;

    float x = Ubuf[(size_t)ts * 16 + li];           // exact at t=T-1
    if (ts < a + K2)
        out[1 + (size_t)ts * 16 + li] = x + PXbuf[(size_t)ts * 16 + li];

    uint4 nA[PD], nB[PD]; float ub[PD], pxb[PD];
    #pragma unroll
    for (int p = 0; p < PD; ++p) {
        int tt = ts - 1 - p;
        if (tt >= a) {
            const unsigned short* rp = &Nbuf[(size_t)tt * 256 + li * 16];
            nA[p]  = *(const uint4*)rp;
            nB[p]  = *(const uint4*)(rp + 8);
            ub[p]  = Ubuf[(size_t)tt * 16 + li];
            pxb[p] = PXbuf[(size_t)tt * 16 + li];
        }
    }

    const int DMAX = K2 - 1 + W2;                   // steps after the head
    for (int db = 1; db <= DMAX; db += PD) {
        #pragma unroll
        for (int q = 0; q < PD; ++q) {
            int t = ts - (db + q);
            if (t >= a) {
                uint4 ra = nA[q], rb = nB[q];
                float ut = ub[q], pxt = pxb[q];
                int tp = t - PD;
                if (tp >= a) {                      // refill ring slot
                    const unsigned short* rp = &Nbuf[(size_t)tp * 256 + li * 16];
                    nA[q]  = *(const uint4*)rp;
                    nB[q]  = *(const uint4*)(rp + 8);
                    ub[q]  = Ubuf[(size_t)tp * 16 + li];
                    pxb[q] = PXbuf[(size_t)tp * 16 + li];
                }
                #define NVL(w) bf2f((unsigned short)((w) & 0xffffu))
                #define NVH(w) bf2f((unsigned short)((w) >> 16))
                float s0 = NVL(ra.x) * bc16<0>(x);
                float s1 = NVH(ra.x) * bc16<1>(x);
                float s2 = NVL(ra.y) * bc16<2>(x);
                float s3 = NVH(ra.y) * bc16<3>(x);
                s0 = fmaf(NVL(ra.z), bc16<4>(x),  s0);
                s1 = fmaf(NVH(ra.z), bc16<5>(x),  s1);
                s2 = fmaf(NVL(ra.w), bc16<6>(x),  s2);
                s3 = fmaf(NVH(ra.w), bc16<7>(x),  s3);
                s0 = fmaf(NVL(rb.x), bc16<8>(x),  s0);
                s1 = fmaf(NVH(rb.x), bc16<9>(x),  s1);
                s2 = fmaf(NVL(rb.y), bc16<10>(x), s2);
                s3 = fmaf(NVH(rb.y), bc16<11>(x), s3);
                s0 = fmaf(NVL(rb.z), bc16<12>(x), s0);
                s1 = fmaf(NVH(rb.z), bc16<13>(x), s1);
                s2 = fmaf(NVL(rb.w), bc16<14>(x), s2);
                s3 = fmaf(NVH(rb.w), bc16<15>(x), s3);
                #undef NVL
                #undef NVH
                x = ut + ((s0 + s1) + (s2 + s3));   // x_t[li]
                if (t < a + K2)
                    out[1 + (size_t)t * 16 + li] = x + pxt;
            }
        }
    }
}

extern "C" void kernel_launch(void* const* d_in, const int* in_sizes, int n_in,
                              void* d_out, int out_size, void* d_ws, size_t ws_size,
                              hipStream_t stream)
{
    const float* data = (const float*)d_in[0];
    const float* Wmu  = (const float*)d_in[1];
    const float* bmu  = (const float*)d_in[2];
    const float* WL   = (const float*)d_in[3];
    const float* bL   = (const float*)d_in[4];
    const float* WLx  = (const float*)d_in[5];
    const float* bLx  = (const float*)d_in[6];
    const float* ns   = (const float*)d_in[7];
    float* out = (float*)d_out;

    unsigned short* Nbuf = (unsigned short*)d_ws;                 // T*256 bf16  (33.5 MB)
    float* Ubuf  = (float*)(Nbuf + (size_t)T_LEN * 256);          // T*16 f32    (4.2 MB)
    float* PXbuf = Ubuf + (size_t)T_LEN * 16;                     // T*16 f32    (4.2 MB)
    float* Sbuf  = PXbuf + (size_t)T_LEN * 16;                    // T*256 f32   (67 MB)
    unsigned short* Cbuf = (unsigned short*)(Sbuf + (size_t)T_LEN * 256); // T*256 bf16 (33.5 MB)
    short* Wsw   = (short*)(Cbuf + (size_t)T_LEN * 256);          // 66*512 bf16

    wswz_kernel<<<dim3(132), dim3(256), 0, stream>>>(Wmu, WL, WLx, Wsw, out);
    vilds_gemm<<<dim3(T_LEN / 16), dim3(256), 0, stream>>>(
        data, Wsw, bmu, bL, bLx, Sbuf, Cbuf, PXbuf);
    vilds_fact<<<dim3(T_LEN / 16), dim3(256), 0, stream>>>(
        Sbuf, Cbuf, ns, Nbuf, Ubuf, out);
    vilds_stage2<<<dim3(T_LEN / (K2 * 4)), dim3(64), 0, stream>>>(Nbuf, Ubuf, PXbuf, out);
}